// Round 13
// baseline (518.128 us; speedup 1.0000x reference)
//
#include <hip/hip_runtime.h>
#include <hip/hip_bf16.h>
#include <math.h>

#define B_ 256
#define I_ 512
#define H_ 512
#define BH (B_*H_)
#define KA 1024          // concat K ([inputs | h0])
#define ROWS 32          // hebb rows per fused block
#define NCHK (H_/ROWS)   // 16 sibling blocks per sample

typedef float f4v  __attribute__((ext_vector_type(4)));
typedef short s8v  __attribute__((ext_vector_type(8)));   // 8 bf16
typedef float f32x4 __attribute__((ext_vector_type(4)));

// ws layout (floats):
// [0, 4*BH)            : pre[g][b][k] gate pre-acts WITH biases
// [4*BH, 5*BH)         : dotws[b][k] cross-block dot accumulators
// [5*BH, 5*BH+256)     : cnt[b] counters (int)
// [5*BH+512, ...)      : bf16 planes Ahi, Alo, Bhi, Blo

#define A_ELEMS (256*1024)
#define B_ELEMS (2048*1024)

// ---------------------------------------------------------------------------
// K-1: zero dotws + cnt (ws is poisoned 0xAA).
// ---------------------------------------------------------------------------
__global__ __launch_bounds__(256) void k_init(float* __restrict__ dotws,
                                              int* __restrict__ cnt) {
    int stride = gridDim.x * blockDim.x;
    for (int f = blockIdx.x * blockDim.x + threadIdx.x; f < BH; f += stride)
        dotws[f] = 0.f;
    int t = blockIdx.x * blockDim.x + threadIdx.x;
    if (t < 256) cnt[t] = 0;
}

// ---------------------------------------------------------------------------
// K0: fp32 -> split-bf16 (hi/lo) planes for the gate GEMM (proven R8/R9).
// ---------------------------------------------------------------------------
__global__ __launch_bounds__(256) void k_convert(
    const float* __restrict__ inputs, const float* __restrict__ h0,
    const float* __restrict__ Wxf, const float* __restrict__ Whf,
    const float* __restrict__ Wxi, const float* __restrict__ Whi,
    const float* __restrict__ Wxo, const float* __restrict__ Who,
    const float* __restrict__ Wxc, const float* __restrict__ w,
    ushort* __restrict__ Ahi, ushort* __restrict__ Alo,
    ushort* __restrict__ Bhi, ushort* __restrict__ Blo) {
    const int NTOT = A_ELEMS + B_ELEMS;
    int stride = gridDim.x * blockDim.x;
    for (int f = blockIdx.x * blockDim.x + threadIdx.x; f < NTOT; f += stride) {
        float x; ushort* dhi; ushort* dlo; int idx;
        if (f < A_ELEMS) {
            idx = f;
            int m = f >> 10, k = f & 1023;
            x = (k < 512) ? inputs[m * 512 + k] : h0[m * 512 + (k - 512)];
            dhi = Ahi; dlo = Alo;
        } else {
            idx = f - A_ELEMS;
            int n = idx >> 10, k = idx & 1023;
            int g = n >> 9, ko = n & 511;
            if (k < 512) {
                const float* W = (g == 0) ? Wxf : (g == 1) ? Wxi : (g == 2) ? Wxo : Wxc;
                x = W[ko * 512 + k];
            } else if (g < 3) {
                const float* W = (g == 0) ? Whf : (g == 1) ? Whi : Who;
                x = W[ko * 512 + (k - 512)];
            } else {
                x = w[(size_t)(k - 512) * 512 + ko];   // transpose of w
            }
            dhi = Bhi; dlo = Blo;
        }
        __hip_bfloat16 h = __float2bfloat16(x);
        float hf = __bfloat162float(h);
        __hip_bfloat16 l = __float2bfloat16(x - hf);
        dhi[idx] = *(ushort*)&h;
        dlo[idx] = *(ushort*)&l;
    }
}

// ---------------------------------------------------------------------------
// K1: gate GEMM via split-bf16 MFMA (proven R8/R9). Biases folded into pre.
// ---------------------------------------------------------------------------
__global__ __launch_bounds__(256) void k_mfma_gates(
    const ushort* __restrict__ Ahi, const ushort* __restrict__ Alo,
    const ushort* __restrict__ Bhi, const ushort* __restrict__ Blo,
    const float* __restrict__ bxf, const float* __restrict__ bhf,
    const float* __restrict__ bxi, const float* __restrict__ bhi,
    const float* __restrict__ bxo, const float* __restrict__ bho,
    const float* __restrict__ bxc,
    float* __restrict__ pre) {
    int wave = threadIdx.x >> 6, lane = threadIdx.x & 63;
    int tile = blockIdx.x * 4 + wave;        // 0..2047
    int m0 = (tile & 15) << 4;
    int n0 = (tile >> 4) << 4;
    int r  = lane & 15;
    int kg = lane >> 4;

    const s8v* pa_hi = (const s8v*)(Ahi + (size_t)(m0 + r) * KA + kg * 8);
    const s8v* pa_lo = (const s8v*)(Alo + (size_t)(m0 + r) * KA + kg * 8);
    const s8v* pb_hi = (const s8v*)(Bhi + (size_t)(n0 + r) * KA + kg * 8);
    const s8v* pb_lo = (const s8v*)(Blo + (size_t)(n0 + r) * KA + kg * 8);

    f32x4 acc = {0.f, 0.f, 0.f, 0.f};
    #pragma unroll 4
    for (int kc = 0; kc < 32; ++kc) {
        s8v ah = pa_hi[kc * 4];
        s8v al = pa_lo[kc * 4];
        s8v bh = pb_hi[kc * 4];
        s8v bl = pb_lo[kc * 4];
        acc = __builtin_amdgcn_mfma_f32_16x16x32_bf16(ah, bh, acc, 0, 0, 0);
        acc = __builtin_amdgcn_mfma_f32_16x16x32_bf16(ah, bl, acc, 0, 0, 0);
        acc = __builtin_amdgcn_mfma_f32_16x16x32_bf16(al, bh, acc, 0, 0, 0);
    }

    int g  = n0 >> 9;
    int ko = (n0 & 511) + r;
    float bias;
    if (g == 0)      bias = bxf[ko] + bhf[ko];
    else if (g == 1) bias = bxi[ko] + bhi[ko];
    else if (g == 2) bias = bxo[ko] + bho[ko];
    else             bias = bxc[ko];
    #pragma unroll
    for (int j = 0; j < 4; ++j) {
        int m = m0 + kg * 4 + j;
        pre[(size_t)g * BH + (size_t)m * H_ + ko] = acc[j] + bias;
    }
}

// ---------------------------------------------------------------------------
// K2: fused single-pass. Block = (b, 32 contiguous hebb ROWS).
// Pass A: contiguous NT read (1 KB/wave/row), reg dot partials for all 512
// cols, stage slab bf16 in LDS. Exchange: 512 atomicAdd + counter spin.
// Finalize all cols redundantly (local myeta). Pass B: update rows, NT store.
// ---------------------------------------------------------------------------
__global__ __launch_bounds__(256) void k_fused(
    const float* __restrict__ hebb, const float* __restrict__ h0,
    const float* __restrict__ pre, const float* __restrict__ c0in,
    const float* __restrict__ alpha,
    const float* __restrict__ Wmod, const float* __restrict__ bmod,
    const float* __restrict__ Wfan, const float* __restrict__ bfan,
    float* __restrict__ dotws, int* __restrict__ cnt,
    float* __restrict__ out) {

    __shared__ ushort sh[ROWS][512];          // 32 KB bf16 slab
    __shared__ float  h0s[ROWS];
    __shared__ float  dotred[128][8];         // [c4][rg*4+j], 4 KB
    __shared__ float  vsh[512] __attribute__((aligned(16)));
    __shared__ float  ered[4];
    __shared__ float  myeta_sh;

    int bid = blockIdx.x;
    int b   = bid >> 4;          // 16 contiguous blocks per sample
    int ch  = bid & 15;
    int t   = threadIdx.x;
    int c4  = t & 127;           // float4 column quad (all 512 cols)
    int rg  = t >> 7;            // 0,1 — row half

    if (t < ROWS) h0s[t] = h0[(size_t)b * H_ + ch * ROWS + t];
    __syncthreads();

    const float* gbase = hebb + (size_t)(b * H_ + ch * ROWS) * H_;

    // ---- pass A: NT contiguous read + dot partial + bf16 stage ----
    f4v acc = {0.f, 0.f, 0.f, 0.f};
    #pragma unroll 8
    for (int i = 0; i < 16; ++i) {
        int row = rg * 16 + i;
        f4v v = __builtin_nontemporal_load(
            (const f4v*)(gbase + (size_t)row * H_ + c4 * 4));
        acc += h0s[row] * v;
        ushort4 u;
        __hip_bfloat16 b0 = __float2bfloat16(v.x); u.x = *(ushort*)&b0;
        __hip_bfloat16 b1 = __float2bfloat16(v.y); u.y = *(ushort*)&b1;
        __hip_bfloat16 b2 = __float2bfloat16(v.z); u.z = *(ushort*)&b2;
        __hip_bfloat16 b3 = __float2bfloat16(v.w); u.w = *(ushort*)&b3;
        *(ushort4*)&sh[row][c4 * 4] = u;
    }
    *(f4v*)&dotred[c4][rg * 4] = acc;
    __syncthreads();

    if (rg == 0) {                            // threads 0..127: 4 cols each
        f4v a = *(const f4v*)&dotred[c4][0] + *(const f4v*)&dotred[c4][4];
        float* dp = dotws + (size_t)b * H_ + c4 * 4;
        atomicAdd(dp + 0, a.x);
        atomicAdd(dp + 1, a.y);
        atomicAdd(dp + 2, a.z);
        atomicAdd(dp + 3, a.w);
    }
    __syncthreads();
    if (t == 0) {
        __hip_atomic_fetch_add(&cnt[b], 1, __ATOMIC_RELEASE,
                               __HIP_MEMORY_SCOPE_AGENT);
        while (__hip_atomic_load(&cnt[b], __ATOMIC_ACQUIRE,
                                 __HIP_MEMORY_SCOPE_AGENT) < NCHK)
            __builtin_amdgcn_s_sleep(1);
    }
    __syncthreads();

    // ---- finalize ALL 512 cols (redundant per block; local myeta) ----
    float c2r[2], ep = 0.f;
    #pragma unroll
    for (int s = 0; s < 2; ++s) {
        int k = t + s * 256;
        size_t off = (size_t)b * H_ + k;
        float dot = __hip_atomic_load(&dotws[off], __ATOMIC_RELAXED,
                                      __HIP_MEMORY_SCOPE_AGENT);
        float pf = pre[0 * BH + off];
        float pi = pre[1 * BH + off];
        float po = pre[2 * BH + off];
        float pc = pre[3 * BH + off];
        float c2 = tanhf(pc + alpha[k] * dot);
        float fg = 1.f / (1.f + expf(-pf));
        float ig = 1.f / (1.f + expf(-pi));
        float og = 1.f / (1.f + expf(-po));
        float cell = fg * c0in[off] + ig * c2;
        float ha = og * tanhf(cell);
        if (ch == 0) {
            out[off] = ha;                    // hactiv
            out[BH + off] = cell;             // cell
        }
        c2r[s] = c2;
        ep += ha * Wmod[k];
    }
    #pragma unroll
    for (int o = 32; o > 0; o >>= 1) ep += __shfl_down(ep, o, 64);
    int wid = t >> 6, lane = t & 63;
    if (lane == 0) ered[wid] = ep;
    __syncthreads();
    if (t == 0)
        myeta_sh = tanhf(ered[0] + ered[1] + ered[2] + ered[3] + bmod[0]);
    __syncthreads();
    float myeta = myeta_sh;
    #pragma unroll
    for (int s = 0; s < 2; ++s) {
        int k = t + s * 256;
        vsh[k] = (myeta * Wfan[k] + bfan[k]) * c2r[s];
    }
    __syncthreads();

    // ---- pass B: update own rows from LDS, NT full-line stores ----
    f4v vq = *(const f4v*)&vsh[c4 * 4];
    float* gout = out + 2 * BH + (size_t)(b * H_ + ch * ROWS) * H_;
    #pragma unroll 8
    for (int i = 0; i < 16; ++i) {
        int row = rg * 16 + i;
        ushort4 u = *(const ushort4*)&sh[row][c4 * 4];
        f4v hb;
        hb.x = __uint_as_float(((unsigned)u.x) << 16);
        hb.y = __uint_as_float(((unsigned)u.y) << 16);
        hb.z = __uint_as_float(((unsigned)u.z) << 16);
        hb.w = __uint_as_float(((unsigned)u.w) << 16);
        f4v r = hb + h0s[row] * vq;
        r.x = fminf(fmaxf(r.x, -2.f), 2.f);
        r.y = fminf(fmaxf(r.y, -2.f), 2.f);
        r.z = fminf(fmaxf(r.z, -2.f), 2.f);
        r.w = fminf(fmaxf(r.w, -2.f), 2.f);
        __builtin_nontemporal_store(r, (f4v*)(gout + (size_t)row * H_ + c4 * 4));
    }
}

// ---------------------------------------------------------------------------
extern "C" void kernel_launch(void* const* d_in, const int* in_sizes, int n_in,
                              void* d_out, int out_size, void* d_ws, size_t ws_size,
                              hipStream_t stream) {
    const float* inputs = (const float*)d_in[0];
    const float* h0     = (const float*)d_in[1];
    const float* c0     = (const float*)d_in[2];
    const float* hebb   = (const float*)d_in[3];
    const float* w      = (const float*)d_in[4];
    const float* alpha  = (const float*)d_in[5];
    const float* Wxf = (const float*)d_in[6];  const float* bxf = (const float*)d_in[7];
    const float* Whf = (const float*)d_in[8];  const float* bhf = (const float*)d_in[9];
    const float* Wxi = (const float*)d_in[10]; const float* bxi = (const float*)d_in[11];
    const float* Whi = (const float*)d_in[12]; const float* bhi = (const float*)d_in[13];
    const float* Wxo = (const float*)d_in[14]; const float* bxo = (const float*)d_in[15];
    const float* Who = (const float*)d_in[16]; const float* bho = (const float*)d_in[17];
    const float* Wxc = (const float*)d_in[18]; const float* bxc = (const float*)d_in[19];
    const float* Wmod = (const float*)d_in[20]; const float* bmod = (const float*)d_in[21];
    const float* Wfan = (const float*)d_in[22]; const float* bfan = (const float*)d_in[23];

    float* out = (float*)d_out;
    float* ws  = (float*)d_ws;
    float*  pre   = ws;                         // 4*BH
    float*  dotws = ws + 4 * BH;                // BH
    int*    cnt   = (int*)(ws + 5 * BH);        // 256 ints
    ushort* Ahi   = (ushort*)(ws + 5 * BH + 512);
    ushort* Alo   = Ahi + A_ELEMS;
    ushort* Bhi   = Alo + A_ELEMS;
    ushort* Blo   = Bhi + B_ELEMS;

    // -1) zero dot accumulators + counters
    k_init<<<256, 256, 0, stream>>>(dotws, cnt);
    // 0) split-bf16 conversion
    k_convert<<<2048, 256, 0, stream>>>(inputs, h0,
        Wxf, Whf, Wxi, Whi, Wxo, Who, Wxc, w, Ahi, Alo, Bhi, Blo);
    // 1) gate GEMM on matrix cores (biases folded)
    k_mfma_gates<<<512, 256, 0, stream>>>(Ahi, Alo, Bhi, Blo,
        bxf, bhf, bxi, bhi, bxo, bho, bxc, pre);
    // 2) fused single-pass: hebb read exactly once, row-major contiguous
    k_fused<<<B_ * NCHK, 256, 0, stream>>>(hebb, h0, pre, c0, alpha,
        Wmod, bmod, Wfan, bfan, dotws, cnt, out);
}

// Round 14
// 160.960 us; speedup vs baseline: 3.2190x; 3.2190x over previous
//
#include <hip/hip_runtime.h>
#include <math.h>

#define B_ 256
#define I_ 512
#define H_ 512
#define BH (B_*H_)
#define NCH 8            // h-chunks for hebbdot partials
#define HCH (H_/NCH)     // 64

typedef float f4v __attribute__((ext_vector_type(4)));

// ws layout (floats):
// [0, 8*BH)        : gate pre-act partials  [ks*4+g][b][k]  (split-K 2)
// [8*BH, 16*BH)    : part[ch][b][k] hebbdot partials

// ---------------------------------------------------------------------------
// K_A: fused (R6 proven, 171.6 structure): blocks [0,1024) gate GEMM
// (split-K x2, 32x32 tile, TK=32, reg-prefetch + LDS dbuf), blocks
// [1024, 3072) hebbdot partials (HBM stream). Gates hide under the stream.
// ---------------------------------------------------------------------------
#define TK 32
#define LDB 34               // padded LDS row stride (floats)
#define TILE_F (TK*LDB)      // 1088 floats per operand buffer
#define NGEMM 1024

__global__ __launch_bounds__(256) void k_dot_gates(
    const float* __restrict__ hebb, const float* __restrict__ h0,
    const float* __restrict__ inputs,
    const float* __restrict__ Wxf, const float* __restrict__ Whf,
    const float* __restrict__ Wxi, const float* __restrict__ Whi,
    const float* __restrict__ Wxo, const float* __restrict__ Who,
    const float* __restrict__ Wxc, const float* __restrict__ w,
    float* __restrict__ pre, float* __restrict__ part) {

    __shared__ float smem[4 * TILE_F];   // 17408 B; aliased by both paths
    int bid = blockIdx.x;
    int tid = threadIdx.x;

    if (bid < NGEMM) {
        // ---------------- gate GEMM path (split-K) ----------------
        int ks = bid & 1;             // 0: inputs@Wx, 1: h0@Wh (or w)
        int m0 = ((bid >> 1) & 7) * 32;
        int n0 = (bid >> 4) * 32;     // [0,2048)
        int g  = n0 >> 9;             // 0=f,1=i,2=o,3=c
        int ko0 = n0 & 511;

        const float* Asrc = ks ? h0 : inputs;
        const float* Bsrc;
        bool wpath = false;
        if (ks == 0) {
            Bsrc = (g == 0) ? Wxf : (g == 1) ? Wxi : (g == 2) ? Wxo : Wxc;
        } else {
            if (g == 3) { Bsrc = w; wpath = true; }
            else Bsrc = (g == 0) ? Whf : (g == 1) ? Whi : Who;
        }

        int row = tid >> 3;          // 0..31
        int c4  = tid & 7;           // float4 index along k (or n for wpath)
        int tx  = tid & 15, ty = tid >> 4;

        float acc[2][2] = {{0.f, 0.f}, {0.f, 0.f}};
        float4 areg, breg;

        auto LOAD = [&](int t) {
            int kb = t * TK;
            areg = *(const float4*)&Asrc[(size_t)(m0 + row) * 512 + kb + c4 * 4];
            if (wpath)
                breg = *(const float4*)&Bsrc[(size_t)(kb + row) * 512 + ko0 + c4 * 4];
            else
                breg = *(const float4*)&Bsrc[(size_t)(ko0 + row) * 512 + kb + c4 * 4];
        };
        auto STORE = [&](int pbuf) {
            float* As = smem + pbuf * 2 * TILE_F;   // [TK][LDB]  (k-major)
            float* Bs = As + TILE_F;
            #pragma unroll
            for (int j = 0; j < 4; ++j)
                As[(c4 * 4 + j) * LDB + row] = ((const float*)&areg)[j];
            if (wpath) {
                #pragma unroll
                for (int j = 0; j < 4; ++j)
                    Bs[row * LDB + c4 * 4 + j] = ((const float*)&breg)[j];
            } else {
                #pragma unroll
                for (int j = 0; j < 4; ++j)
                    Bs[(c4 * 4 + j) * LDB + row] = ((const float*)&breg)[j];
            }
        };

        LOAD(0);
        STORE(0);
        for (int t = 0; t < 16; ++t) {
            __syncthreads();
            if (t < 15) LOAD(t + 1);
            int pb = t & 1;
            const float* As = smem + pb * 2 * TILE_F;
            const float* Bs = As + TILE_F;
            #pragma unroll
            for (int kk = 0; kk < TK; ++kk) {
                float2 a2 = *(const float2*)&As[kk * LDB + ty * 2];
                float2 b2 = *(const float2*)&Bs[kk * LDB + tx * 2];
                acc[0][0] += a2.x * b2.x; acc[0][1] += a2.x * b2.y;
                acc[1][0] += a2.y * b2.x; acc[1][1] += a2.y * b2.y;
            }
            if (t < 15) STORE(pb ^ 1);
        }

        float* pb_out = pre + (size_t)(ks * 4 + g) * BH;
        #pragma unroll
        for (int i = 0; i < 2; ++i) {
            #pragma unroll
            for (int j = 0; j < 2; ++j) {
                int bnum = m0 + ty * 2 + i;
                int ko = ko0 + tx * 2 + j;
                pb_out[(size_t)bnum * H_ + ko] = acc[i][j];
            }
        }
    } else {
        // ---------------- hebbdot path ----------------
        int hbid = bid - NGEMM;
        int b  = hbid >> 3;    // consecutive blocks share b -> contiguous hebb
        int ch = hbid & 7;

        float*  h0s = smem;                    // [64]
        float4* red = (float4*)(smem + 64);    // [256]

        if (tid < HCH) h0s[tid] = h0[b * H_ + ch * HCH + tid];
        __syncthreads();

        const float4* hbp = (const float4*)(hebb + ((size_t)b * H_ + (size_t)ch * HCH) * H_);
        int tk = tid & 127;    // float4 column
        int th = tid >> 7;     // 0,1 — split h range
        float4 acc = make_float4(0.f, 0.f, 0.f, 0.f);
        #pragma unroll 8
        for (int r = 0; r < 32; ++r) {
            int hh = th * 32 + r;
            float s = h0s[hh];
            float4 vv = hbp[(size_t)hh * 128 + tk];
            acc.x += s * vv.x; acc.y += s * vv.y;
            acc.z += s * vv.z; acc.w += s * vv.w;
        }
        red[tid] = acc;
        __syncthreads();
        if (tid < 128) {
            float4 a = red[tid], c = red[tid + 128];
            float4 o = make_float4(a.x + c.x, a.y + c.y, a.z + c.z, a.w + c.w);
            ((float4*)(part + ((size_t)ch * B_ + b) * H_))[tid] = o;
        }
    }
}

// ---------------------------------------------------------------------------
// K_B: finalize + update merged. 2048 blocks, REVERSE slab order (L3-warm
// tail first). Block rb=(2047-bid): b = rb>>3, 64-row slab ch = rb&7.
// Phase 1: redundantly compute v[b,:] (part+pre L2/L3-resident), ch==0
// writes hactiv/cell. Phase 2: update slab, plain loads + NT stores.
// ---------------------------------------------------------------------------
__global__ __launch_bounds__(256) void k_updatev(
    const float* __restrict__ hebb, const float* __restrict__ h0,
    const float* __restrict__ pre, const float* __restrict__ part,
    const float* __restrict__ c0in, const float* __restrict__ alpha,
    const float* __restrict__ bxf, const float* __restrict__ bhf,
    const float* __restrict__ bxi, const float* __restrict__ bhi,
    const float* __restrict__ bxo, const float* __restrict__ bho,
    const float* __restrict__ bxc,
    const float* __restrict__ Wmod, const float* __restrict__ bmod,
    const float* __restrict__ Wfan, const float* __restrict__ bfan,
    float* __restrict__ out) {

    __shared__ float vsh[512] __attribute__((aligned(16)));
    __shared__ float h0s[64];
    __shared__ float red[4];
    __shared__ float myeta_sh;

    int rb = 2047 - (int)blockIdx.x;    // reverse dispatch -> reverse memory
    int b  = rb >> 3;
    int ch = rb & 7;
    int t  = threadIdx.x;

    // ---- phase 1: v[b,:] (redundant per block) ----
    float c2r[2], ep = 0.f;
    #pragma unroll
    for (int s = 0; s < 2; ++s) {
        int k = t + s * 256;
        float dot = 0.f;
        #pragma unroll
        for (int c = 0; c < NCH; ++c) dot += part[((size_t)c * B_ + b) * H_ + k];
        size_t off = (size_t)b * H_ + k;
        float pf = pre[0 * BH + off] + pre[4 * BH + off] + bxf[k] + bhf[k];
        float pi = pre[1 * BH + off] + pre[5 * BH + off] + bxi[k] + bhi[k];
        float po = pre[2 * BH + off] + pre[6 * BH + off] + bxo[k] + bho[k];
        float pc = pre[3 * BH + off] + pre[7 * BH + off] + bxc[k];
        float c2 = tanhf(pc + alpha[k] * dot);
        float fg = 1.f / (1.f + expf(-pf));
        float ig = 1.f / (1.f + expf(-pi));
        float og = 1.f / (1.f + expf(-po));
        float cell = fg * c0in[off] + ig * c2;
        float ha = og * tanhf(cell);
        if (ch == 0) {
            out[off] = ha;                 // hactiv
            out[BH + off] = cell;          // cell
        }
        c2r[s] = c2;
        ep += ha * Wmod[k];
    }
    #pragma unroll
    for (int o = 32; o > 0; o >>= 1) ep += __shfl_down(ep, o, 64);
    int wid = t >> 6, lane = t & 63;
    if (lane == 0) red[wid] = ep;
    if (t < 64) h0s[t] = h0[(size_t)b * H_ + ch * 64 + t];
    __syncthreads();
    if (t == 0)
        myeta_sh = tanhf(red[0] + red[1] + red[2] + red[3] + bmod[0]);
    __syncthreads();
    float myeta = myeta_sh;
    #pragma unroll
    for (int s = 0; s < 2; ++s) {
        int k = t + s * 256;
        vsh[k] = (myeta * Wfan[k] + bfan[k]) * c2r[s];
    }
    __syncthreads();

    // ---- phase 2: update 64-row slab, plain loads (L3-warm) + NT stores ----
    int c4 = t & 127;                   // float4 column quad
    int rg = t >> 7;                    // 0,1
    const float4* gin  = (const float4*)(hebb + (size_t)(b * H_ + ch * 64) * H_) + c4;
    f4v*          gout = (f4v*)(out + 2 * BH + (size_t)(b * H_ + ch * 64) * H_) + c4;
    f4v vq = *(const f4v*)&vsh[c4 * 4];
    #pragma unroll 8
    for (int i = 0; i < 32; ++i) {
        int row = i * 2 + rg;           // 0..63
        float u = h0s[row];
        float4 hb4 = gin[(size_t)row * 128];
        f4v r;
        r.x = fminf(fmaxf(hb4.x + u * vq.x, -2.f), 2.f);
        r.y = fminf(fmaxf(hb4.y + u * vq.y, -2.f), 2.f);
        r.z = fminf(fmaxf(hb4.z + u * vq.z, -2.f), 2.f);
        r.w = fminf(fmaxf(hb4.w + u * vq.w, -2.f), 2.f);
        __builtin_nontemporal_store(r, gout + (size_t)row * 128);
    }
}

// ---------------------------------------------------------------------------
extern "C" void kernel_launch(void* const* d_in, const int* in_sizes, int n_in,
                              void* d_out, int out_size, void* d_ws, size_t ws_size,
                              hipStream_t stream) {
    const float* inputs = (const float*)d_in[0];
    const float* h0     = (const float*)d_in[1];
    const float* c0     = (const float*)d_in[2];
    const float* hebb   = (const float*)d_in[3];
    const float* w      = (const float*)d_in[4];
    const float* alpha  = (const float*)d_in[5];
    const float* Wxf = (const float*)d_in[6];  const float* bxf = (const float*)d_in[7];
    const float* Whf = (const float*)d_in[8];  const float* bhf = (const float*)d_in[9];
    const float* Wxi = (const float*)d_in[10]; const float* bxi = (const float*)d_in[11];
    const float* Whi = (const float*)d_in[12]; const float* bhi = (const float*)d_in[13];
    const float* Wxo = (const float*)d_in[14]; const float* bxo = (const float*)d_in[15];
    const float* Who = (const float*)d_in[16]; const float* bho = (const float*)d_in[17];
    const float* Wxc = (const float*)d_in[18]; const float* bxc = (const float*)d_in[19];
    const float* Wmod = (const float*)d_in[20]; const float* bmod = (const float*)d_in[21];
    const float* Wfan = (const float*)d_in[22]; const float* bfan = (const float*)d_in[23];

    float* out = (float*)d_out;
    float* ws  = (float*)d_ws;
    float* pre  = ws;                  // 8*BH (split-K partials, no bias)
    float* part = ws + 8 * BH;         // 8*BH

    // 1) fused: hebbdot stream + latency-tolerant scalar split-K GEMM
    k_dot_gates<<<NGEMM + B_ * NCH, 256, 0, stream>>>(
        hebb, h0, inputs,
        Wxf, Whf, Wxi, Whi, Wxo, Who, Wxc, w, pre, part);
    // 2) finalize + update merged (reverse slab order, NT stores)
    k_updatev<<<2048, 256, 0, stream>>>(
        hebb, h0, pre, part, c0, alpha,
        bxf, bhf, bxi, bhi, bxo, bho, bxc,
        Wmod, bmod, Wfan, bfan, out);
}